// Round 1
// 284.066 us; speedup vs baseline: 1.0046x; 1.0046x over previous
//
#include <hip/hip_runtime.h>
#include <math.h>

#define MASK_FILL_F (-987654321.0f)

typedef unsigned short u16;
typedef unsigned int   u32;

constexpr int Bb   = 64;
constexpr int Ntok = 197;
constexpr int Dim  = 768;
constexpr int Heads= 12;
constexpr int Dh   = 64;
constexpr int Nq3  = 2304;      // 3*Dim
constexpr int Rows = 12608;     // 64*197
constexpr int Mpad = 12672;     // 99*128 (ws row padding; virtual pad to 12800 for 256-tiles is overflow-safe)

using f32x4  = __attribute__((ext_vector_type(4))) float;
using bf16x8 = __attribute__((ext_vector_type(8))) short;   // 8 bf16 (4 VGPRs)

__device__ __forceinline__ u16 f2bf(float f) {          // RNE float->bf16
  u32 u = __float_as_uint(f);
  u = (u + 0x7fffu + ((u >> 16) & 1u)) >> 16;
  return (u16)u;
}

__device__ __forceinline__ void stage16(const void* gp, void* lp) {
  __builtin_amdgcn_global_load_lds(
      (const __attribute__((address_space(1))) u32*)gp,
      (__attribute__((address_space(3))) u32*)lp, 16, 0, 0);
}

// sigma: inverse of the MFMA slot->C-row bit map (verified round 5).
__device__ __forceinline__ int sigma6(int M) {
  return (M & 0x23) | (((M >> 3) & 1) << 4) | (((M >> 2) & 1) << 3) |
         (((M >> 4) & 1) << 2);
}

// ---------------------------------------------------------------------------
__global__ __launch_bounds__(256) void cvt_bf16(const float* __restrict__ in,
                                                u16* __restrict__ out, int n4) {
  const int i = blockIdx.x * 256 + threadIdx.x;
  if (i < n4) {
    const float4 v = *(const float4*)&in[(size_t)i * 4];
    ushort4 u;
    u.x = f2bf(v.x); u.y = f2bf(v.y); u.z = f2bf(v.z); u.w = f2bf(v.w);
    *(ushort4*)&out[(size_t)i * 4] = u;
  }
}

// ---------------------------------------------------------------------------
__global__ __launch_bounds__(256) void transpose_cvt(const float* __restrict__ in,
                                                     u16* __restrict__ out,
                                                     int R, int C) {
  __shared__ float t[32][33];
  const int c0 = blockIdx.x * 32, r0 = blockIdx.y * 32;
  const int tx = threadIdx.x & 31, ty = threadIdx.x >> 5;
#pragma unroll
  for (int rr = ty; rr < 32; rr += 8)
    t[rr][tx] = in[(size_t)(r0 + rr) * C + c0 + tx];
  __syncthreads();
#pragma unroll
  for (int cc = ty; cc < 32; cc += 8)
    out[(size_t)(c0 + cc) * R + r0 + tx] = f2bf(t[tx][cc]);
}

// ---------------------------------------------------------------------------
// V pre-transpose -> vT[bh][d][jpad=256], zero-padded (verified round 5).
// ---------------------------------------------------------------------------
__global__ __launch_bounds__(256) void vtrans(const u16* __restrict__ qkvB,
                                              u16* __restrict__ vT) {
  __shared__ u16 t[64 * 72];
  const int jt = blockIdx.x, bh = blockIdx.y;
  const int b = bh / Heads, h = bh % Heads;
  const int j0 = jt * 64;
  const int tid = threadIdx.x;

  for (int idx = tid; idx < 512; idx += 256) {
    const int jr = idx >> 3, c8 = (idx & 7) * 8;
    const int j = j0 + jr;
    uint4 u = make_uint4(0u, 0u, 0u, 0u);
    if (j < Ntok)
      u = *(const uint4*)(qkvB + (size_t)(b * Ntok + j) * Nq3 + 2 * Dim + h * Dh + c8);
    *(uint4*)&t[jr * 72 + c8] = u;
  }
  __syncthreads();
  for (int idx = tid; idx < 512; idx += 256) {
    const int d = idx >> 3, j8 = (idx & 7) * 8;
    ushort4 lo, hi;
    lo.x = t[(j8 + 0) * 72 + d]; lo.y = t[(j8 + 1) * 72 + d];
    lo.z = t[(j8 + 2) * 72 + d]; lo.w = t[(j8 + 3) * 72 + d];
    hi.x = t[(j8 + 4) * 72 + d]; hi.y = t[(j8 + 5) * 72 + d];
    hi.z = t[(j8 + 6) * 72 + d]; hi.w = t[(j8 + 7) * 72 + d];
    u16* dst = vT + ((size_t)bh * 64 + d) * 256 + j0 + j8;
    *(ushort4*)dst       = lo;
    *(ushort4*)(dst + 4) = hi;
  }
}

// ---------------------------------------------------------------------------
// 256x256 / 8-wave / BK=64 8-phase bf16 GEMM (guide §5 template, m201).
//   T1: bijective XCD swizzle.  T2: slot^(row&7) XOR swizzle, applied as
//   pre-swizzled GLOBAL source (LDS dest of global_load_lds stays linear).
//   T3: 4 phases/K-tile, each {ds_read subtile || 2x global_load_lds ||
//       barrier || 16 MFMA (T5 setprio) || counted vmcnt || barrier}.
//   T4: per-thread issue order per tile = A1,B1,A2,B2,B3,B4,A3,A4.
//       Consumption: ph0 {A-h0,B-h0}, ph1 {B-h1}, ph2 {A-h1}, ph3 {B-h0 reuse}
//       -> steady waits vmcnt(4) at end of ph0/ph1/ph3; epilogue tile 2->0.
//       Raw s_barrier (asm) so loads stay in flight; NEVER __syncthreads.
// MODE 0: rotary epilogue, bf16 C.  MODE 1: +bias, fp32 C, row guard.
// M virtually padded to 12800: overflow A-reads hit adjacent ws regions
// (defined); MODE-0 overflow C-writes land in attnB head, rewritten by attn7
// before gemm<1> reads it; MODE-1 rows guarded by row<Rows.
// ---------------------------------------------------------------------------
constexpr int Kc  = 768;
constexpr int NKT = Kc / 64;    // 12 K-tiles

#define BARM() asm volatile("s_barrier" ::: "memory")
#define VMW4() asm volatile("s_waitcnt vmcnt(4)" ::: "memory")
#define VMW2() asm volatile("s_waitcnt vmcnt(2)" ::: "memory")
#define VMW0() asm volatile("s_waitcnt vmcnt(0)" ::: "memory")

#define PH(MH, NH, RDA, RDB, STG, ...)                                         \
  do {                                                                         \
    if (RDA) {                                                                 \
      _Pragma("unroll") for (int m_ = 0; m_ < 4; ++m_)                         \
      _Pragma("unroll") for (int k_ = 0; k_ < 2; ++k_)                         \
        af[m_][k_] = *(const bf16x8*)&Asb[((MH) * 64 + mrow + m_ * 16) * 64    \
                                          + (((k_ * 4 + qd) ^ sx) * 8)];       \
    }                                                                          \
    if (RDB) {                                                                 \
      _Pragma("unroll") for (int n_ = 0; n_ < 2; ++n_)                         \
      _Pragma("unroll") for (int k_ = 0; k_ < 2; ++k_)                         \
        bfr[n_][k_] = *(const bf16x8*)&Bsb[((NH) * 32 + nrow + n_ * 16) * 64   \
                                           + (((k_ * 4 + qd) ^ sx) * 8)];      \
    }                                                                          \
    STG;                                                                       \
    BARM();                                                                    \
    __builtin_amdgcn_s_setprio(1);                                             \
    _Pragma("unroll") for (int m_ = 0; m_ < 4; ++m_)                           \
    _Pragma("unroll") for (int n_ = 0; n_ < 2; ++n_)                           \
    _Pragma("unroll") for (int k_ = 0; k_ < 2; ++k_)                           \
      acc[(MH) * 4 + m_][(NH) * 2 + n_] =                                      \
          __builtin_amdgcn_mfma_f32_16x16x32_bf16(                             \
              af[m_][k_], bfr[n_][k_],                                         \
              acc[(MH) * 4 + m_][(NH) * 2 + n_], 0, 0, 0);                     \
    __builtin_amdgcn_s_setprio(0);                                             \
    __VA_ARGS__;                                                               \
    BARM();                                                                    \
  } while (0)

template<int MODE, int TN>
__global__ __launch_bounds__(512, 2) void gemm8p(
    const u16* __restrict__ Ag, const u16* __restrict__ Bg,
    void* __restrict__ Cv, int Nn, int nwg,
    const float* __restrict__ pe, const float* __restrict__ bias)
{
  __shared__ u16 As[2][256 * 64];   // 32 KB each half -> 128 KiB total
  __shared__ u16 Bs[2][256 * 64];

  const int tid = threadIdx.x, lane = tid & 63, w = tid >> 6;

  // T1: bijective XCD swizzle (m204 formula)
  const int orig = blockIdx.x;
  const int q8 = nwg >> 3, r8 = nwg & 7;
  const int xcd = orig & 7, sub = orig >> 3;
  const int wgid = (xcd < r8 ? xcd * (q8 + 1) : r8 * (q8 + 1) + (xcd - r8) * q8) + sub;
  const int tm = wgid / TN, tn = wgid % TN;
  const int m0 = tm * 256, n0 = tn * 256;

  const int wr = w >> 2, wc = w & 3;               // 2M x 4N waves
  const int tx = lane & 15, qd = lane >> 4, sx = tx & 7;
  const int mrow = wr * 128 + tx, nrow = wc * 64 + tx;

  // staging geometry: chunk = 8 rows x 64 cols (1024 B), linear LDS dest,
  // pre-swizzled global source: lane l -> row 8c+(l>>3), colgrp (l&7)^(l>>3)
  const int srow = lane >> 3;
  const int scol = ((lane & 7) ^ srow) * 8;
  const int a1c = (w & 1) * 16 + (w >> 1) * 2, a2c = a1c + 1;
  const int a3c = a1c + 8,                     a4c = a2c + 8;
  const int b1c = (w & 3) * 8 + (w >> 2) * 2,  b2c = b1c + 1;
  const int b3c = b1c + 4,                     b4c = b2c + 4;

  const u16* sA1 = Ag + (size_t)(m0 + 8 * a1c + srow) * Kc + scol;
  const u16* sA2 = Ag + (size_t)(m0 + 8 * a2c + srow) * Kc + scol;
  const u16* sA3 = Ag + (size_t)(m0 + 8 * a3c + srow) * Kc + scol;
  const u16* sA4 = Ag + (size_t)(m0 + 8 * a4c + srow) * Kc + scol;
  const u16* sB1 = Bg + (size_t)(n0 + 8 * b1c + srow) * Kc + scol;
  const u16* sB2 = Bg + (size_t)(n0 + 8 * b2c + srow) * Kc + scol;
  const u16* sB3 = Bg + (size_t)(n0 + 8 * b3c + srow) * Kc + scol;
  const u16* sB4 = Bg + (size_t)(n0 + 8 * b4c + srow) * Kc + scol;

  // prologue: stage K-tile 0 into buf 0 (positional order!), vmcnt(4), barrier
  stage16(sA1, &As[0][a1c * 512]); stage16(sB1, &Bs[0][b1c * 512]);
  stage16(sA2, &As[0][a2c * 512]); stage16(sB2, &Bs[0][b2c * 512]);
  stage16(sB3, &Bs[0][b3c * 512]); stage16(sB4, &Bs[0][b4c * 512]);
  stage16(sA3, &As[0][a3c * 512]); stage16(sA4, &As[0][a4c * 512]);
  sA1 += 64; sA2 += 64; sA3 += 64; sA4 += 64;
  sB1 += 64; sB2 += 64; sB3 += 64; sB4 += 64;
  VMW4();
  BARM();

  f32x4  acc[8][4] = {};
  bf16x8 af[4][2], bfr[2][2];

  int cur = 0;
#pragma unroll 1
  for (int t = 0; t < NKT - 1; ++t) {
    const u16* Asb = As[cur];
    const u16* Bsb = Bs[cur];
    u16* An = As[cur ^ 1];
    u16* Bn = Bs[cur ^ 1];

    PH(0, 0, 1, 1,
       { stage16(sA1, &An[a1c * 512]); stage16(sB1, &Bn[b1c * 512]); }, VMW4());
    PH(0, 1, 0, 1,
       { stage16(sA2, &An[a2c * 512]); stage16(sB2, &Bn[b2c * 512]); }, VMW4());
    PH(1, 1, 1, 0,
       { stage16(sB3, &Bn[b3c * 512]); stage16(sB4, &Bn[b4c * 512]); }, );
    PH(1, 0, 0, 1,
       { stage16(sA3, &An[a3c * 512]); stage16(sA4, &An[a4c * 512]); }, VMW4());

    sA1 += 64; sA2 += 64; sA3 += 64; sA4 += 64;
    sB1 += 64; sB2 += 64; sB3 += 64; sB4 += 64;
    cur ^= 1;
  }
  { // peeled final tile: no staging, drain 2 -> 0
    const u16* Asb = As[cur];
    const u16* Bsb = Bs[cur];
    PH(0, 0, 1, 1, {}, VMW2());
    PH(0, 1, 0, 1, {}, VMW0());
    PH(1, 1, 1, 0, {}, );
    PH(1, 0, 0, 1, {}, );
  }

  // ---- epilogue (round-5-verified per-element code, 8-wave geometry) ----
  if (MODE == 0) {
    u16* C = (u16*)Cv;
    const bool dorot = (n0 < 2 * Dim);
#pragma unroll
    for (int mi = 0; mi < 8; ++mi) {
      const int rbase = m0 + wr * 128 + mi * 16 + qd * 4;
      int iq[4];
#pragma unroll
      for (int r = 0; r < 4; ++r) iq[r] = (rbase + r) % Ntok;
#pragma unroll
      for (int ni = 0; ni < 4; ++ni) {
        const int col = n0 + wc * 64 + ni * 16 + tx;
        const int mm  = (col & 63) >> 1;
        const int odd = col & 1;
#pragma unroll
        for (int r = 0; r < 4; ++r) {
          float v = acc[mi][ni][r];
          float res = v;
          if (dorot) {
            const float other = __shfl_xor(v, 1, 64);
            const float sn = pe[iq[r] * 64 + mm];
            const float c2 = pe[iq[r] * 64 + 32 + mm];
            res = odd ? (v * c2 + other * sn) : (v * c2 - other * sn);
          }
          C[(size_t)(rbase + r) * Nn + col] = f2bf(res);
        }
      }
    }
  } else {
    float* C = (float*)Cv;
#pragma unroll
    for (int mi = 0; mi < 8; ++mi) {
      const int rbase = m0 + wr * 128 + mi * 16 + qd * 4;
#pragma unroll
      for (int ni = 0; ni < 4; ++ni) {
        const int col = n0 + wc * 64 + ni * 16 + tx;
        const float bv = bias[col];
#pragma unroll
        for (int r = 0; r < 4; ++r) {
          const int row = rbase + r;
          if (row < Rows) C[(size_t)row * Nn + col] = acc[mi][ni][r] + bv;
        }
      }
    }
  }
}

// ---------------------------------------------------------------------------
// MFMA flash attention v7 (round-5-verified structure + single-pass
// unnormalized softmax) — unchanged this round.
// ---------------------------------------------------------------------------
constexpr int LS = 72;

__global__ __launch_bounds__(256) void attn7(
    const u16* __restrict__ qkvB, const u16* __restrict__ vT,
    const float* __restrict__ scale, u16* __restrict__ outB)
{
  __shared__ u16 ks [64 * LS];   // K [sigma-permuted j][d]
  __shared__ u16 vts[64 * LS];   // V^T[d][j]

  const int it = blockIdx.x, bh = blockIdx.y;
  const int b = bh / Heads, h = bh % Heads;
  const int i0 = it * 128;
  const float sc = scale[h];
  const int tid = threadIdx.x, lane = tid & 63, w = tid >> 6;
  const int tx = lane & 15, q = lane >> 4;
  const size_t rowbase = (size_t)b * Ntok;

  // ---- Q fragments straight to registers (rows i0+32w+16g+tx) ----
  bf16x8 bq[2][2];
#pragma unroll
  for (int g = 0; g < 2; ++g)
#pragma unroll
    for (int kk = 0; kk < 2; ++kk)
      bq[g][kk] = *(const bf16x8*)(qkvB +
          (rowbase + i0 + 32 * w + 16 * g + tx) * (size_t)Nq3 + h * Dh + kk * 32 + q * 8);

  float l_part[2] = {0.f, 0.f};     // per-lane partial sum of p
  f32x4 oacc[2][4] = {};            // O[i = 32w+16g+4q+r][d = nb*16+tx]

  for (int jt = 0; jt < 4; ++jt) {
    const int j0 = jt * 64;
    __syncthreads();               // prev tile's ks/vts reads done

    for (int idx = tid; idx < 512; idx += 256) {
      const int M = idx >> 3, c8 = (idx & 7) * 8;
      const int js = sigma6(M);
      *(uint4*)&ks[M * LS + c8] =
          *(const uint4*)(qkvB + (rowbase + j0 + js) * (size_t)Nq3 + Dim + h * Dh + c8);
    }
    for (int idx = tid; idx < 512; idx += 256) {
      const int d = idx >> 3, c8 = (idx & 7) * 8;
      *(uint4*)&vts[d * LS + c8] =
          *(const uint4*)(vT + ((size_t)bh * 64 + d) * 256 + j0 + c8);
    }
    __syncthreads();

#pragma unroll
    for (int g = 0; g < 2; ++g) {
      // ---- S^T = K(sigma)·Q^T ----
      f32x4 sT[4] = {};
#pragma unroll
      for (int kk = 0; kk < 2; ++kk)
#pragma unroll
        for (int jb = 0; jb < 4; ++jb) {
          const bf16x8 ka = *(const bf16x8*)&ks[(jb * 16 + tx) * LS + kk * 32 + q * 8];
          sT[jb] = __builtin_amdgcn_mfma_f32_16x16x32_bf16(ka, bq[g][kk], sT[jb], 0, 0, 0);
        }

      // ---- single-pass: p = exp(s*sc), masked; pack P for PV ----
      const int ig = i0 + 32 * w + 16 * g + tx;
      union { bf16x8 v; u16 e[8]; } pk[2];
      float lp = 0.f;
#pragma unroll
      for (int jb = 0; jb < 4; ++jb)
#pragma unroll
        for (int r = 0; r < 4; ++r) {
          const int jg = j0 + 32 * (jb >> 1) + 8 * q + 4 * (jb & 1) + r;
          const float s = fminf(sT[jb][r] * sc, 80.f);
          const bool bad = (jg >= Ntok) || (jg == ig);
          const float p = bad ? 0.f : __expf(s);
          lp += p;
          pk[jb >> 1].e[(jb & 1) * 4 + r] = f2bf(p);
        }
      l_part[g] += lp;

      // ---- O += P·V ----
#pragma unroll
      for (int kk = 0; kk < 2; ++kk)
#pragma unroll
        for (int nb = 0; nb < 4; ++nb) {
          const bf16x8 vb = *(const bf16x8*)&vts[(nb * 16 + tx) * LS + kk * 32 + q * 8];
          oacc[g][nb] = __builtin_amdgcn_mfma_f32_16x16x32_bf16(pk[kk].v, vb,
                                                               oacc[g][nb], 0, 0, 0);
        }
    }
  }

  // ---- epilogue: reduce l over quads, normalize, per-element stores ----
#pragma unroll
  for (int g = 0; g < 2; ++g) {
    float l = l_part[g];
    l += __shfl_xor(l, 16, 64);
    l += __shfl_xor(l, 32, 64);      // row total (row = tx within this g)
    const float linv = 1.0f / l;
#pragma unroll
    for (int r = 0; r < 4; ++r) {
      const float lr = __shfl(linv, 4 * q + r, 64);
      const int igr = i0 + 32 * w + 16 * g + 4 * q + r;
      if (igr < Ntok) {
#pragma unroll
        for (int nb = 0; nb < 4; ++nb)
          outB[(rowbase + igr) * (size_t)Dim + h * Dh + nb * 16 + tx] =
              f2bf(oacc[g][nb][r] * lr);
      }
    }
  }
}

// ---------------------------------------------------------------------------
extern "C" void kernel_launch(void* const* d_in, const int* in_sizes, int n_in,
                              void* d_out, int out_size, void* d_ws, size_t ws_size,
                              hipStream_t stream) {
  const float* x     = (const float*)d_in[0];
  const float* pe    = (const float*)d_in[1];
  const float* w_qkv = (const float*)d_in[2];
  const float* scale = (const float*)d_in[3];
  const float* w_out = (const float*)d_in[4];
  const float* b_out = (const float*)d_in[5];
  float* out = (float*)d_out;

  u16* xb    = (u16*)d_ws;                       // [Mpad][768]
  u16* wqkvT = xb    + (size_t)Mpad * Dim;       // [2304][768]
  u16* woutT = wqkvT + (size_t)Nq3 * Dim;        // [768][768]
  u16* qkvB  = woutT + (size_t)Dim * Dim;        // [Mpad][2304]
  u16* attnB = qkvB  + (size_t)Mpad * Nq3;       // [Mpad][768]
  u16* vT    = attnB + (size_t)Mpad * Dim;       // [768][64][256]

  cvt_bf16<<<(Rows * Dim / 4 + 255) / 256, 256, 0, stream>>>(x, xb, Rows * Dim / 4);
  transpose_cvt<<<dim3(Nq3 / 32, Dim / 32), 256, 0, stream>>>(w_qkv, wqkvT, Dim, Nq3);
  transpose_cvt<<<dim3(Dim / 32, Dim / 32), 256, 0, stream>>>(w_out, woutT, Dim, Dim);

  // QKV GEMM: M(virt)=12800 -> 50 row-tiles, N=2304 -> 9 col-tiles
  constexpr int NWG0 = 50 * 9;
  gemm8p<0, 9><<<NWG0, 512, 0, stream>>>(xb, wqkvT, qkvB, Nq3, NWG0, pe, nullptr);

  vtrans<<<dim3(4, Bb * Heads), 256, 0, stream>>>(qkvB, vT);

  attn7<<<dim3(2, Bb * Heads), 256, 0, stream>>>(qkvB, vT, scale, attnB);

  // out GEMM: N=768 -> 3 col-tiles
  constexpr int NWG1 = 50 * 3;
  gemm8p<1, 3><<<NWG1, 512, 0, stream>>>(attnB, woutT, out, Dim, NWG1, nullptr, b_out);
}

// Round 2
// 282.852 us; speedup vs baseline: 1.0089x; 1.0043x over previous
//
#include <hip/hip_runtime.h>
#include <math.h>

#define MASK_FILL_F (-987654321.0f)

typedef unsigned short u16;
typedef unsigned int   u32;

constexpr int Bb   = 64;
constexpr int Ntok = 197;
constexpr int Dim  = 768;
constexpr int Heads= 12;
constexpr int Dh   = 64;
constexpr int Nq3  = 2304;      // 3*Dim
constexpr int Rows = 12608;     // 64*197
constexpr int Mpad = 12672;     // 99*128 (ws row padding; virtual pad to 12800 for 256-tiles is overflow-safe)

using f32x4  = __attribute__((ext_vector_type(4))) float;
using bf16x8 = __attribute__((ext_vector_type(8))) short;   // 8 bf16 (4 VGPRs)

__device__ __forceinline__ u16 f2bf(float f) {          // RNE float->bf16
  u32 u = __float_as_uint(f);
  u = (u + 0x7fffu + ((u >> 16) & 1u)) >> 16;
  return (u16)u;
}

__device__ __forceinline__ void stage16(const void* gp, void* lp) {
  __builtin_amdgcn_global_load_lds(
      (const __attribute__((address_space(1))) u32*)gp,
      (__attribute__((address_space(3))) u32*)lp, 16, 0, 0);
}

// sigma: inverse of the MFMA slot->C-row bit map (verified round 5).
__device__ __forceinline__ int sigma6(int M) {
  return (M & 0x23) | (((M >> 3) & 1) << 4) | (((M >> 2) & 1) << 3) |
         (((M >> 4) & 1) << 2);
}

// ---------------------------------------------------------------------------
__global__ __launch_bounds__(256) void cvt_bf16(const float* __restrict__ in,
                                                u16* __restrict__ out, int n4) {
  const int i = blockIdx.x * 256 + threadIdx.x;
  if (i < n4) {
    const float4 v = *(const float4*)&in[(size_t)i * 4];
    ushort4 u;
    u.x = f2bf(v.x); u.y = f2bf(v.y); u.z = f2bf(v.z); u.w = f2bf(v.w);
    *(ushort4*)&out[(size_t)i * 4] = u;
  }
}

// ---------------------------------------------------------------------------
__global__ __launch_bounds__(256) void transpose_cvt(const float* __restrict__ in,
                                                     u16* __restrict__ out,
                                                     int R, int C) {
  __shared__ float t[32][33];
  const int c0 = blockIdx.x * 32, r0 = blockIdx.y * 32;
  const int tx = threadIdx.x & 31, ty = threadIdx.x >> 5;
#pragma unroll
  for (int rr = ty; rr < 32; rr += 8)
    t[rr][tx] = in[(size_t)(r0 + rr) * C + c0 + tx];
  __syncthreads();
#pragma unroll
  for (int cc = ty; cc < 32; cc += 8)
    out[(size_t)(c0 + cc) * R + r0 + tx] = f2bf(t[tx][cc]);
}

// ---------------------------------------------------------------------------
// V pre-transpose -> vT[bh][d][jpad=256], zero-padded (verified round 5).
// ---------------------------------------------------------------------------
__global__ __launch_bounds__(256) void vtrans(const u16* __restrict__ qkvB,
                                              u16* __restrict__ vT) {
  __shared__ u16 t[64 * 72];
  const int jt = blockIdx.x, bh = blockIdx.y;
  const int b = bh / Heads, h = bh % Heads;
  const int j0 = jt * 64;
  const int tid = threadIdx.x;

  for (int idx = tid; idx < 512; idx += 256) {
    const int jr = idx >> 3, c8 = (idx & 7) * 8;
    const int j = j0 + jr;
    uint4 u = make_uint4(0u, 0u, 0u, 0u);
    if (j < Ntok)
      u = *(const uint4*)(qkvB + (size_t)(b * Ntok + j) * Nq3 + 2 * Dim + h * Dh + c8);
    *(uint4*)&t[jr * 72 + c8] = u;
  }
  __syncthreads();
  for (int idx = tid; idx < 512; idx += 256) {
    const int d = idx >> 3, j8 = (idx & 7) * 8;
    ushort4 lo, hi;
    lo.x = t[(j8 + 0) * 72 + d]; lo.y = t[(j8 + 1) * 72 + d];
    lo.z = t[(j8 + 2) * 72 + d]; lo.w = t[(j8 + 3) * 72 + d];
    hi.x = t[(j8 + 4) * 72 + d]; hi.y = t[(j8 + 5) * 72 + d];
    hi.z = t[(j8 + 6) * 72 + d]; hi.w = t[(j8 + 7) * 72 + d];
    u16* dst = vT + ((size_t)bh * 64 + d) * 256 + j0 + j8;
    *(ushort4*)dst       = lo;
    *(ushort4*)(dst + 4) = hi;
  }
}

// ---------------------------------------------------------------------------
// 256x256 / 8-wave / BK=64 GEMM, derived-waits 8-phase (2 K-tiles / iter).
//
// Groups (match per-phase READ sets exactly):
//   A-grp(MH) = rows { wr*128 + MH*64 .. +63 }  = chunks {bit3==MH}
//   B-grp(NH) = rows { wc*64  + NH*32 .. +31 }  = chunks {bit2==NH}
// Every wave stages 2 chunks of EVERY group (symmetric vmcnt positions):
//   A0: {w,16+w}  A1: {8+w,24+w}  B0: {b0,b0+1}  B1: {b0+4,b0+5},
//   b0 = (w>>1)*8 + (w&1)*2.
// Iteration i computes tiles u=2i (buf0) and u+1 (buf1), quadrant order
// (00),(01),(11),(10) with register reuse (ph3/ph7: zero ds_reads).
// Staging (1 group = 2 loads per phase, all >=3 phases before first read):
//   ph0:A1(u+1)->b1  ph1:B0(u+1)->b1  ph2:A0(u+2)->b0  ph3:B1(u+2)->b0
//   ph4:A1(u+2)->b0  ph5:B0(u+2)->b0  ph6:A0(u+3)->b1  ph7:B1(u+3)->b1
// Each staged region's last LDS read precedes its stage by >=1 barrier
// (register reuse makes ph3/ph7 readless - verified group by group).
// Waits: vmcnt(4) at end of ph3 and ph7 ONLY (never 0 in the loop); each
// transitively covers all first-uses of the next 4 phases with >=3-phase
// slack. Uniform loop; last iter prefetches tiles 12/13 = garbage reads
// into adjacent allocated ws regions, never consumed.
// ---------------------------------------------------------------------------
constexpr int Kc  = 768;
constexpr int NKT = Kc / 64;    // 12 K-tiles -> 6 iterations

#define BARM() asm volatile("s_barrier" ::: "memory")
#define VMW4() asm volatile("s_waitcnt vmcnt(4)" ::: "memory")

#define STGA(chunk, kt, BUF) \
  stage16(Ag + (size_t)(m0 + (chunk) * 8 + srow) * Kc + (kt) * 64 + scol, \
          &As[BUF][(chunk) * 512])
#define STGB(chunk, kt, BUF) \
  stage16(Bg + (size_t)(n0 + (chunk) * 8 + srow) * Kc + (kt) * 64 + scol, \
          &Bs[BUF][(chunk) * 512])

#define RDA(BUF, MH) \
  _Pragma("unroll") for (int m_ = 0; m_ < 4; ++m_) \
  _Pragma("unroll") for (int k_ = 0; k_ < 2; ++k_) \
    af[m_][k_] = *(const bf16x8*)&As[BUF][(wr * 128 + (MH) * 64 + m_ * 16 + tx) * 64 \
                                          + (((k_ * 4 + qd) ^ sx) * 8)];
#define RDB(BUF, NH, BFR) \
  _Pragma("unroll") for (int n_ = 0; n_ < 2; ++n_) \
  _Pragma("unroll") for (int k_ = 0; k_ < 2; ++k_) \
    BFR[n_][k_] = *(const bf16x8*)&Bs[BUF][(wc * 64 + (NH) * 32 + n_ * 16 + tx) * 64 \
                                           + (((k_ * 4 + qd) ^ sx) * 8)];

#define MM(MH, NH, BFR) \
  __builtin_amdgcn_s_setprio(1); \
  _Pragma("unroll") for (int m_ = 0; m_ < 4; ++m_) \
  _Pragma("unroll") for (int n_ = 0; n_ < 2; ++n_) \
  _Pragma("unroll") for (int k_ = 0; k_ < 2; ++k_) \
    acc[(MH) * 4 + m_][(NH) * 2 + n_] = __builtin_amdgcn_mfma_f32_16x16x32_bf16( \
        af[m_][k_], BFR[n_][k_], acc[(MH) * 4 + m_][(NH) * 2 + n_], 0, 0, 0); \
  __builtin_amdgcn_s_setprio(0);

template<int MODE, int TN>
__global__ __launch_bounds__(512, 2) void gemm8p(
    const u16* __restrict__ Ag, const u16* __restrict__ Bg,
    void* __restrict__ Cv, int Nn, int nwg,
    const float* __restrict__ pe, const float* __restrict__ bias)
{
  __shared__ u16 As[2][256 * 64];   // 128 KiB total with Bs
  __shared__ u16 Bs[2][256 * 64];

  const int tid = threadIdx.x, lane = tid & 63, w = tid >> 6;

  // T1: bijective XCD swizzle (m204 formula)
  const int orig = blockIdx.x;
  const int q8 = nwg >> 3, r8 = nwg & 7;
  const int xcd = orig & 7, sub = orig >> 3;
  const int wgid = (xcd < r8 ? xcd * (q8 + 1) : r8 * (q8 + 1) + (xcd - r8) * q8) + sub;
  const int tm = wgid / TN, tn = wgid % TN;
  const int m0 = tm * 256, n0 = tn * 256;

  const int wr = w >> 2, wc = w & 3;               // 2M x 4N waves
  const int tx = lane & 15, qd = lane >> 4, sx = tx & 7;

  // staging geometry: chunk = 8 rows x 64 cols (1024 B), linear LDS dest,
  // pre-swizzled global source: lane l -> row 8c+(l>>3), colgrp (l&7)^(l>>3)
  const int srow = lane >> 3;
  const int scol = ((lane & 7) ^ srow) * 8;
  const int b0 = (w >> 1) * 8 + (w & 1) * 2;

  // ---- prologue: tile0 (all 4 groups) + tile1 (A0,B1), steady order ----
  STGA(w, 0, 0);        STGA(16 + w, 0, 0);       // A0(0)
  STGB(b0 + 4, 0, 0);   STGB(b0 + 5, 0, 0);       // B1(0)
  STGA(8 + w, 0, 0);    STGA(24 + w, 0, 0);       // A1(0)
  STGB(b0, 0, 0);       STGB(b0 + 1, 0, 0);       // B0(0)
  STGA(w, 1, 1);        STGA(16 + w, 1, 1);       // A0(1)
  STGB(b0 + 4, 1, 1);   STGB(b0 + 5, 1, 1);       // B1(1)
  VMW4();               // tile0 fully resident; A0(1),B1(1) in flight
  BARM();

  f32x4  acc[8][4] = {};
  bf16x8 af[4][2], bf0[2][2], bf1[2][2];

#pragma unroll 1
  for (int i = 0; i < NKT / 2; ++i) {
    const int u = 2 * i;
    // ph0: Q(00) tile u | stage A1(u+1)->buf1
    RDA(0, 0); RDB(0, 0, bf0);
    STGA(8 + w, u + 1, 1); STGA(24 + w, u + 1, 1);
    BARM(); MM(0, 0, bf0); BARM();
    // ph1: Q(01) | stage B0(u+1)->buf1
    RDB(0, 1, bf1);
    STGB(b0, u + 1, 1); STGB(b0 + 1, u + 1, 1);
    BARM(); MM(0, 1, bf1); BARM();
    // ph2: Q(11) | stage A0(u+2)->buf0
    RDA(0, 1);
    STGA(w, u + 2, 0); STGA(16 + w, u + 2, 0);
    BARM(); MM(1, 1, bf1); BARM();
    // ph3: Q(10) (pure register reuse) | stage B1(u+2)->buf0 | vmcnt(4)
    STGB(b0 + 4, u + 2, 0); STGB(b0 + 5, u + 2, 0);
    BARM(); MM(1, 0, bf0); VMW4(); BARM();
    // ph4: Q(00) tile u+1 | stage A1(u+2)->buf0
    RDA(1, 0); RDB(1, 0, bf0);
    STGA(8 + w, u + 2, 0); STGA(24 + w, u + 2, 0);
    BARM(); MM(0, 0, bf0); BARM();
    // ph5: Q(01) | stage B0(u+2)->buf0
    RDB(1, 1, bf1);
    STGB(b0, u + 2, 0); STGB(b0 + 1, u + 2, 0);
    BARM(); MM(0, 1, bf1); BARM();
    // ph6: Q(11) | stage A0(u+3)->buf1
    RDA(1, 1);
    STGA(w, u + 3, 1); STGA(16 + w, u + 3, 1);
    BARM(); MM(1, 1, bf1); BARM();
    // ph7: Q(10) (register reuse) | stage B1(u+3)->buf1 | vmcnt(4)
    STGB(b0 + 4, u + 3, 1); STGB(b0 + 5, u + 3, 1);
    BARM(); MM(1, 0, bf0); VMW4(); BARM();
  }

  // ---- epilogue (round-5-verified per-element code, 8-wave geometry) ----
  if (MODE == 0) {
    u16* C = (u16*)Cv;
    const bool dorot = (n0 < 2 * Dim);
#pragma unroll
    for (int mi = 0; mi < 8; ++mi) {
      const int rbase = m0 + wr * 128 + mi * 16 + qd * 4;
      int iq[4];
#pragma unroll
      for (int r = 0; r < 4; ++r) iq[r] = (rbase + r) % Ntok;
#pragma unroll
      for (int ni = 0; ni < 4; ++ni) {
        const int col = n0 + wc * 64 + ni * 16 + tx;
        const int mm  = (col & 63) >> 1;
        const int odd = col & 1;
#pragma unroll
        for (int r = 0; r < 4; ++r) {
          float v = acc[mi][ni][r];
          float res = v;
          if (dorot) {
            const float other = __shfl_xor(v, 1, 64);
            const float sn = pe[iq[r] * 64 + mm];
            const float c2 = pe[iq[r] * 64 + 32 + mm];
            res = odd ? (v * c2 + other * sn) : (v * c2 - other * sn);
          }
          C[(size_t)(rbase + r) * Nn + col] = f2bf(res);
        }
      }
    }
  } else {
    float* C = (float*)Cv;
#pragma unroll
    for (int mi = 0; mi < 8; ++mi) {
      const int rbase = m0 + wr * 128 + mi * 16 + qd * 4;
#pragma unroll
      for (int ni = 0; ni < 4; ++ni) {
        const int col = n0 + wc * 64 + ni * 16 + tx;
        const float bv = bias[col];
#pragma unroll
        for (int r = 0; r < 4; ++r) {
          const int row = rbase + r;
          if (row < Rows) C[(size_t)row * Nn + col] = acc[mi][ni][r] + bv;
        }
      }
    }
  }
}

// ---------------------------------------------------------------------------
// MFMA flash attention v7 (round-5-verified structure + single-pass
// unnormalized softmax) — unchanged this round.
// ---------------------------------------------------------------------------
constexpr int LS = 72;

__global__ __launch_bounds__(256) void attn7(
    const u16* __restrict__ qkvB, const u16* __restrict__ vT,
    const float* __restrict__ scale, u16* __restrict__ outB)
{
  __shared__ u16 ks [64 * LS];   // K [sigma-permuted j][d]
  __shared__ u16 vts[64 * LS];   // V^T[d][j]

  const int it = blockIdx.x, bh = blockIdx.y;
  const int b = bh / Heads, h = bh % Heads;
  const int i0 = it * 128;
  const float sc = scale[h];
  const int tid = threadIdx.x, lane = tid & 63, w = tid >> 6;
  const int tx = lane & 15, q = lane >> 4;
  const size_t rowbase = (size_t)b * Ntok;

  // ---- Q fragments straight to registers (rows i0+32w+16g+tx) ----
  bf16x8 bq[2][2];
#pragma unroll
  for (int g = 0; g < 2; ++g)
#pragma unroll
    for (int kk = 0; kk < 2; ++kk)
      bq[g][kk] = *(const bf16x8*)(qkvB +
          (rowbase + i0 + 32 * w + 16 * g + tx) * (size_t)Nq3 + h * Dh + kk * 32 + q * 8);

  float l_part[2] = {0.f, 0.f};     // per-lane partial sum of p
  f32x4 oacc[2][4] = {};            // O[i = 32w+16g+4q+r][d = nb*16+tx]

  for (int jt = 0; jt < 4; ++jt) {
    const int j0 = jt * 64;
    __syncthreads();               // prev tile's ks/vts reads done

    for (int idx = tid; idx < 512; idx += 256) {
      const int M = idx >> 3, c8 = (idx & 7) * 8;
      const int js = sigma6(M);
      *(uint4*)&ks[M * LS + c8] =
          *(const uint4*)(qkvB + (rowbase + j0 + js) * (size_t)Nq3 + Dim + h * Dh + c8);
    }
    for (int idx = tid; idx < 512; idx += 256) {
      const int d = idx >> 3, c8 = (idx & 7) * 8;
      *(uint4*)&vts[d * LS + c8] =
          *(const uint4*)(vT + ((size_t)bh * 64 + d) * 256 + j0 + c8);
    }
    __syncthreads();

#pragma unroll
    for (int g = 0; g < 2; ++g) {
      // ---- S^T = K(sigma)·Q^T ----
      f32x4 sT[4] = {};
#pragma unroll
      for (int kk = 0; kk < 2; ++kk)
#pragma unroll
        for (int jb = 0; jb < 4; ++jb) {
          const bf16x8 ka = *(const bf16x8*)&ks[(jb * 16 + tx) * LS + kk * 32 + q * 8];
          sT[jb] = __builtin_amdgcn_mfma_f32_16x16x32_bf16(ka, bq[g][kk], sT[jb], 0, 0, 0);
        }

      // ---- single-pass: p = exp(s*sc), masked; pack P for PV ----
      const int ig = i0 + 32 * w + 16 * g + tx;
      union { bf16x8 v; u16 e[8]; } pk[2];
      float lp = 0.f;
#pragma unroll
      for (int jb = 0; jb < 4; ++jb)
#pragma unroll
        for (int r = 0; r < 4; ++r) {
          const int jg = j0 + 32 * (jb >> 1) + 8 * q + 4 * (jb & 1) + r;
          const float s = fminf(sT[jb][r] * sc, 80.f);
          const bool bad = (jg >= Ntok) || (jg == ig);
          const float p = bad ? 0.f : __expf(s);
          lp += p;
          pk[jb >> 1].e[(jb & 1) * 4 + r] = f2bf(p);
        }
      l_part[g] += lp;

      // ---- O += P·V ----
#pragma unroll
      for (int kk = 0; kk < 2; ++kk)
#pragma unroll
        for (int nb = 0; nb < 4; ++nb) {
          const bf16x8 vb = *(const bf16x8*)&vts[(nb * 16 + tx) * LS + kk * 32 + q * 8];
          oacc[g][nb] = __builtin_amdgcn_mfma_f32_16x16x32_bf16(pk[kk].v, vb,
                                                               oacc[g][nb], 0, 0, 0);
        }
    }
  }

  // ---- epilogue: reduce l over quads, normalize, per-element stores ----
#pragma unroll
  for (int g = 0; g < 2; ++g) {
    float l = l_part[g];
    l += __shfl_xor(l, 16, 64);
    l += __shfl_xor(l, 32, 64);      // row total (row = tx within this g)
    const float linv = 1.0f / l;
#pragma unroll
    for (int r = 0; r < 4; ++r) {
      const float lr = __shfl(linv, 4 * q + r, 64);
      const int igr = i0 + 32 * w + 16 * g + 4 * q + r;
      if (igr < Ntok) {
#pragma unroll
        for (int nb = 0; nb < 4; ++nb)
          outB[(rowbase + igr) * (size_t)Dim + h * Dh + nb * 16 + tx] =
              f2bf(oacc[g][nb][r] * lr);
      }
    }
  }
}

// ---------------------------------------------------------------------------
extern "C" void kernel_launch(void* const* d_in, const int* in_sizes, int n_in,
                              void* d_out, int out_size, void* d_ws, size_t ws_size,
                              hipStream_t stream) {
  const float* x     = (const float*)d_in[0];
  const float* pe    = (const float*)d_in[1];
  const float* w_qkv = (const float*)d_in[2];
  const float* scale = (const float*)d_in[3];
  const float* w_out = (const float*)d_in[4];
  const float* b_out = (const float*)d_in[5];
  float* out = (float*)d_out;

  u16* xb    = (u16*)d_ws;                       // [Mpad][768]
  u16* wqkvT = xb    + (size_t)Mpad * Dim;       // [2304][768]
  u16* woutT = wqkvT + (size_t)Nq3 * Dim;        // [768][768]
  u16* qkvB  = woutT + (size_t)Dim * Dim;        // [Mpad][2304]
  u16* attnB = qkvB  + (size_t)Mpad * Nq3;       // [Mpad][768]
  u16* vT    = attnB + (size_t)Mpad * Dim;       // [768][64][256]

  cvt_bf16<<<(Rows * Dim / 4 + 255) / 256, 256, 0, stream>>>(x, xb, Rows * Dim / 4);
  transpose_cvt<<<dim3(Nq3 / 32, Dim / 32), 256, 0, stream>>>(w_qkv, wqkvT, Dim, Nq3);
  transpose_cvt<<<dim3(Dim / 32, Dim / 32), 256, 0, stream>>>(w_out, woutT, Dim, Dim);

  // QKV GEMM: M(virt)=12800 -> 50 row-tiles, N=2304 -> 9 col-tiles
  constexpr int NWG0 = 50 * 9;
  gemm8p<0, 9><<<NWG0, 512, 0, stream>>>(xb, wqkvT, qkvB, Nq3, NWG0, pe, nullptr);

  vtrans<<<dim3(4, Bb * Heads), 256, 0, stream>>>(qkvB, vT);

  attn7<<<dim3(2, Bb * Heads), 256, 0, stream>>>(qkvB, vT, scale, attnB);

  // out GEMM: N=768 -> 3 col-tiles
  constexpr int NWG1 = 50 * 3;
  gemm8p<1, 3><<<NWG1, 512, 0, stream>>>(attnB, woutT, out, Dim, NWG1, nullptr, b_out);
}